// Round 5
// baseline (197.823 us; speedup 1.0000x reference)
//
#include <hip/hip_runtime.h>
#include <hip/hip_fp16.h>

// TrigHashGrid: B=1048576, IN_DIM=3, M=3, N=16, C=2, W=1000, A=-0.75
// R9: ABLATION PROBE. R6/R8 latency fixes all null; kernel ~75us with no
// pipe >38% at 61% occupancy. R7 gave marginal cost 2.4us/iter for the FULL
// body. This round: identical R8 real loop (16 iters, bitwise-identical
// output) + 12 GHOST iterations = full sin/weight compute + x replay loads
// but NO ldstap reads / interp / store, sunk via asm volatile (keeps chain
// live, rule #17). Ghost marginal vs 2.4 full marginal splits the cost:
//   bench ~210, VALUBusy>=50% -> compute-chain bound -> instr diet + ILP
//   bench ~196                -> LDS+store bound -> tap/store restructure
//   time grows, VALUBusy flat -> issue/clock effect, neither pipe story

constexpr float A_C = -0.75f;

#define BLK 1024
#define WPAD 1004            // 2 + 1000 + 2 positions, one __half2 each

__device__ __forceinline__ float hw_sin(float a) {
    // sin(a) = v_sin_f32(fract(a / 2pi)); v_fract wraps negatives correctly.
    float rev = a * 0.15915494309189535f;
    rev = __builtin_amdgcn_fractf(rev);
    return __builtin_amdgcn_sinf(rev);
}

// Compute one iteration's interpolation stage: packed fp16 weights + tap ptr.
__device__ __forceinline__ void make_stage(
    float x0, float x1, float x2,
    const float G0[3], const float G1[3], const float G2[3], const float Hr[3],
    const __half2* lrow,
    __half2& W0, __half2& W1, __half2& W2, __half2& W3,
    const __half2*& tap)
{
    float p = 1.0f;
#pragma unroll
    for (int m = 0; m < 3; ++m) {
        float a = fmaf(x0, G0[m], fmaf(x1, G1[m], fmaf(x2, G2[m], Hr[m])));
        p *= hw_sin(a);
    }
    float ix = fmaf(p, 500.0f, 499.5f);                // [-0.5, 999.5]
    float xf = floorf(ix);
    float t  = ix - xf;
    int base = (int)xf;                                // [-1, 999]
    base = min(max(base, -1), 999);                    // cheap insurance

    float u   = 1.0f - t;
    float tu  = t * u;
    float atu = A_C * tu;
    float w0  = atu * u;
    float w3  = atu * t;
    float w1  = fmaf(fmaf(A_C + 2.0f, t, -(A_C + 3.0f)), t * t, 1.0f);
    float w2  = 1.0f - w0 - w1 - w3;

    W0 = __float2half2_rn(w0);
    W1 = __float2half2_rn(w1);
    W2 = __float2half2_rn(w2);
    W3 = __float2half2_rn(w3);
    tap = lrow + (base + 1);                           // padded idx >= 0
}

__global__ __launch_bounds__(BLK, 8)
void trig_hashgrid(const float* __restrict__ x, const float* __restrict__ grids,
                   const float* __restrict__ G, const float* __restrict__ H,
                   float* __restrict__ out)
{
    __shared__ __half2 lds[8 * WPAD];         // 32128 B
    const int tid  = threadIdx.x;
    const int half = blockIdx.x & 1;          // which 8 of the 16 levels
    const int blk  = blockIdx.x >> 1;         // 0..511

    if (tid < 32) {
        int nl = tid >> 2, j = tid & 3;
        int off = (j < 2) ? j : (WPAD - 4 + j);
        lds[nl * WPAD + off] = __floats2half2_rn(0.0f, 0.0f);
    }
    {
        int row = tid >> 7;                   // 0..7 (level within half)
        int j   = tid & 127;
        const float* gsrc = grids + half * 16000 + row * 2000;
        __half2* ldst = lds + row * WPAD;
        for (int w = j; w < 1000; w += 128)
            ldst[w + 2] = __floats2half2_rn(gsrc[w], gsrc[1000 + w]);
    }

    const int n_loc = tid & 7;
    const int n     = half * 8 + n_loc;       // fixed per thread
    const int g     = tid >> 3;               // 0..127

    float G0[3], G1[3], G2[3], Hr[3];
#pragma unroll
    for (int m = 0; m < 3; ++m) {
        G0[m] = G[0 * 48 + m * 16 + n];
        G1[m] = G[1 * 48 + m * 16 + n];
        G2[m] = G[2 * 48 + m * 16 + n];
        Hr[m] = H[m * 16 + n];
    }
    __syncthreads();

    float2* __restrict__ out2 = (float2*)out;
    const __half2* lrow = &lds[n_loc * WPAD];

    // ---- REAL loop: identical to R8 (16 iters, depth-1 tap pipeline) ----
    int b  = blk * 128 + g;
    int b1 = b + 65536;

    float y0, y1, y2;
    __half2 W0, W1, W2, W3, t0, t1, t2, t3;
    const __half2* tp;

    {
        float x0 = x[b * 3 + 0], x1 = x[b * 3 + 1], x2 = x[b * 3 + 2];
        make_stage(x0, x1, x2, G0, G1, G2, Hr, lrow, W0, W1, W2, W3, tp);
        t0 = tp[0]; t1 = tp[1]; t2 = tp[2]; t3 = tp[3];
        y0 = x[b1 * 3 + 0]; y1 = x[b1 * 3 + 1]; y2 = x[b1 * 3 + 2];
    }

#pragma unroll 3
    for (int i = 0; i < 15; ++i) {
        __half2 nW0, nW1, nW2, nW3;
        const __half2* ntp;
        make_stage(y0, y1, y2, G0, G1, G2, Hr, lrow, nW0, nW1, nW2, nW3, ntp);
        __half2 u0 = ntp[0], u1 = ntp[1], u2 = ntp[2], u3 = ntp[3];
        int b2 = (i < 14) ? b1 + 65536 : b1;
        float z0 = x[b2 * 3 + 0], z1 = x[b2 * 3 + 1], z2 = x[b2 * 3 + 2];
        __half2 acc = __hmul2(t0, W0);
        acc = __hfma2(t1, W1, acc);
        acc = __hfma2(t2, W2, acc);
        acc = __hfma2(t3, W3, acc);
        out2[b * 16 + n] = __half22float2(acc);
        b = b1; b1 = b2;
        y0 = z0; y1 = z1; y2 = z2;
        W0 = nW0; W1 = nW1; W2 = nW2; W3 = nW3;
        t0 = u0;  t1 = u1;  t2 = u2;  t3 = u3;
    }

    {
        __half2 acc = __hmul2(t0, W0);
        acc = __hfma2(t1, W1, acc);
        acc = __hfma2(t2, W2, acc);
        acc = __hfma2(t3, W3, acc);
        out2[b * 16 + n] = __half22float2(acc);
    }

    // ---- GHOST loop: 12 compute-only replay iterations (no LDS read, no
    // interp, no store). Same x replay pattern as R7's extra reps (L2-hot).
    // asm sinks keep weights + tap pointer (hence the whole sin chain and
    // the x loads) live -- ablation isolates the LDS+interp+store lump.
    {
        int gb = blk * 128 + g;
        float gx0 = x[gb * 3 + 0], gx1 = x[gb * 3 + 1], gx2 = x[gb * 3 + 2];
#pragma unroll 3
        for (int i = 0; i < 12; ++i) {
            int gbn = gb + 65536;
            float gy0 = x[gbn * 3 + 0];
            float gy1 = x[gbn * 3 + 1];
            float gy2 = x[gbn * 3 + 2];
            __half2 gW0, gW1, gW2, gW3;
            const __half2* gtp;
            make_stage(gx0, gx1, gx2, G0, G1, G2, Hr, lrow,
                       gW0, gW1, gW2, gW3, gtp);
            unsigned s0 = *(unsigned*)&gW0, s1 = *(unsigned*)&gW1;
            unsigned s2 = *(unsigned*)&gW2, s3 = *(unsigned*)&gW3;
            unsigned sp = (unsigned)(unsigned long long)gtp;
            asm volatile("" :: "v"(s0), "v"(s1), "v"(s2), "v"(s3), "v"(sp));
            gb = gbn; gx0 = gy0; gx1 = gy1; gx2 = gy2;
        }
        asm volatile("" :: "v"(gx0), "v"(gx1), "v"(gx2));
    }
}

extern "C" void kernel_launch(void* const* d_in, const int* in_sizes, int n_in,
                              void* d_out, int out_size, void* d_ws, size_t ws_size,
                              hipStream_t stream) {
    const float* x     = (const float*)d_in[0];
    const float* grids = (const float*)d_in[1];
    const float* G     = (const float*)d_in[2];
    const float* H     = (const float*)d_in[3];
    float* out = (float*)d_out;
    trig_hashgrid<<<1024, BLK, 0, stream>>>(x, grids, G, H, out);
}

// Round 7
// 173.126 us; speedup vs baseline: 1.1427x; 1.1427x over previous
//
#include <hip/hip_runtime.h>
#include <hip/hip_fp16.h>

// TrigHashGrid: B=1048576, IN_DIM=3, M=3, N=16, C=2, W=1000, A=-0.75
// R11 = R10 with the compile fix: __builtin_nontemporal_store needs a
// native clang vector (ext_vector_type), not HIP's float4 class.
// R10 theory (unchanged): R9 ablation showed tap+interp+store lump =
// 1.5us/iter (64% of marginal), measured WITH the R8 pipeline => issue/BW,
// not latency. Write path is the largest pipe demand (8MB/iter ~1.2us at
// 6.6TB/s) and the old pattern was hostile: 64B segments with 64B holes,
// other half of every 128B line written by the paired block on another XCD.
// Fix: one block = all 16 levels (fp16 LDS 64.25KB, 2 blocks/CU); thread
// owns level pair (2np,2np+1) -> one float4 store = full quarter-line;
// wave store = 1KB contiguous full 128B lines, single writer; nontemporal
// (output never re-read). Store instrs halve; x read once per b; two
// independent sin->tap chains per thread (real ILP). Numerics == R8.

constexpr float A_C = -0.75f;

#define BLK 1024
#define WPAD 1004            // 2 + 1000 + 2 positions, one __half2 each

typedef float f32x4 __attribute__((ext_vector_type(4)));

__device__ __forceinline__ float hw_sin(float a) {
    // sin(a) = v_sin_f32(fract(a / 2pi)); v_fract wraps negatives correctly.
    float rev = a * 0.15915494309189535f;
    rev = __builtin_amdgcn_fractf(rev);
    return __builtin_amdgcn_sinf(rev);
}

__global__ __launch_bounds__(BLK, 8)
void trig_hashgrid(const float* __restrict__ x, const float* __restrict__ grids,
                   const float* __restrict__ G, const float* __restrict__ H,
                   float* __restrict__ out)
{
    __shared__ __half2 lds[16 * WPAD];        // 64256 B -> 2 blocks/CU
    const int tid = threadIdx.x;
    const int blk = blockIdx.x;               // 0..511

    // Zero the 4 pad positions per level row (padded w {0,1,1002,1003}).
    if (tid < 64) {
        int nl = tid >> 2, j = tid & 3;
        int off = (j < 2) ? j : (WPAD - 4 + j);
        lds[nl * WPAD + off] = __floats2half2_rn(0.0f, 0.0f);
    }
    // Stage all 16 levels as packed half2(c0,c1); 64 lanes/row, coalesced.
    {
        int row = tid >> 6;                   // 0..15
        int j   = tid & 63;
        const float* gsrc = grids + row * 2000;
        __half2* ldst = lds + row * WPAD;
        for (int w = j; w < 1000; w += 64)
            ldst[w + 2] = __floats2half2_rn(gsrc[w], gsrc[1000 + w]);
    }

    const int np = tid & 7;                   // level pair: n = 2np, 2np+1
    const int g  = tid >> 3;                  // 0..127
    const int n0 = 2 * np, n1 = n0 + 1;

    // Per-pair frequencies/phases in registers (reused 16 iters).
    float Ga[2][3], Gb[2][3], Gc[2][3], Hh[2][3];
#pragma unroll
    for (int m = 0; m < 3; ++m) {
        Ga[0][m] = G[0*48 + m*16 + n0]; Ga[1][m] = G[0*48 + m*16 + n1];
        Gb[0][m] = G[1*48 + m*16 + n0]; Gb[1][m] = G[1*48 + m*16 + n1];
        Gc[0][m] = G[2*48 + m*16 + n0]; Gc[1][m] = G[2*48 + m*16 + n1];
        Hh[0][m] = H[m*16 + n0];        Hh[1][m] = H[m*16 + n1];
    }
    __syncthreads();

    f32x4* __restrict__ out4 = (f32x4*)out;
    const __half2* lrow0 = &lds[n0 * WPAD];
    const __half2* lrow1 = &lds[n1 * WPAD];

    // 16 iterations, b stride 65536; two independent chains per thread.
#pragma unroll 2
    for (int i = 0; i < 16; ++i) {
        int b = blk * 128 + g + i * 65536;
        float x0 = x[b * 3 + 0];
        float x1 = x[b * 3 + 1];
        float x2 = x[b * 3 + 2];

        float2 o[2];
#pragma unroll
        for (int s = 0; s < 2; ++s) {
            float p = 1.0f;
#pragma unroll
            for (int m = 0; m < 3; ++m) {
                float a = fmaf(x0, Ga[s][m],
                          fmaf(x1, Gb[s][m],
                          fmaf(x2, Gc[s][m], Hh[s][m])));
                p *= hw_sin(a);
            }
            float ix = fmaf(p, 500.0f, 499.5f);        // [-0.5, 999.5]
            float xf = floorf(ix);
            float t  = ix - xf;
            int base = (int)xf;                        // [-1, 999]
            base = min(max(base, -1), 999);            // cheap insurance

            // Factored Keys weights.
            float u   = 1.0f - t;
            float tu  = t * u;
            float atu = A_C * tu;
            float w0  = atu * u;
            float w3  = atu * t;
            float w1  = fmaf(fmaf(A_C + 2.0f, t, -(A_C + 3.0f)), t * t, 1.0f);
            float w2  = 1.0f - w0 - w1 - w3;

            // 4 consecutive padded taps starting at padded index base+1 >= 0.
            const __half2* tap = (s ? lrow1 : lrow0) + (base + 1);
            __half2 acc = __hmul2(tap[0], __float2half2_rn(w0));
            acc = __hfma2(tap[1], __float2half2_rn(w1), acc);
            acc = __hfma2(tap[2], __float2half2_rn(w2), acc);
            acc = __hfma2(tap[3], __float2half2_rn(w3), acc);
            o[s] = __half22float2(acc);
        }

        // out[b, n, c] flat = b*32 + n*2 + c -> float4 at b*8 + np holds
        // (n0c0, n0c1, n1c0, n1c1). Wave = 8 b x 8 np -> 1KB contiguous,
        // full 128B lines, single writer. Nontemporal: never re-read.
        f32x4 v = { o[0].x, o[0].y, o[1].x, o[1].y };
        __builtin_nontemporal_store(v, &out4[b * 8 + np]);
    }
}

extern "C" void kernel_launch(void* const* d_in, const int* in_sizes, int n_in,
                              void* d_out, int out_size, void* d_ws, size_t ws_size,
                              hipStream_t stream) {
    const float* x     = (const float*)d_in[0];
    const float* grids = (const float*)d_in[1];
    const float* G     = (const float*)d_in[2];
    const float* H     = (const float*)d_in[3];
    float* out = (float*)d_out;
    trig_hashgrid<<<512, BLK, 0, stream>>>(x, grids, G, H, out);
}